// Round 6
// baseline (155.323 us; speedup 1.0000x reference)
//
#include <hip/hip_runtime.h>
#include <math.h>
#include <stdint.h>

#define B_  16
#define N_  512
#define C_  384
#define K_  64
#define NN_ (N_*N_)   // 262144

typedef short bf16x8 __attribute__((ext_vector_type(8)));
typedef float f32x4  __attribute__((ext_vector_type(4)));

// fp32 -> bf16 round-to-nearest-even (inputs finite, no NaN path needed)
__device__ __forceinline__ unsigned short f2bf(float f) {
    union { float f; unsigned u; } v; v.f = f;
    unsigned r = v.u + 0x7FFF + ((v.u >> 16) & 1);
    return (unsigned short)(r >> 16);
}
__device__ __forceinline__ unsigned pack2(float a, float b) {
    return ((unsigned)f2bf(b) << 16) | f2bf(a);
}

// async 16-B global -> LDS (lane-contiguous LDS dest required)
__device__ __forceinline__ void gl_lds16(const void* g, void* l) {
    __builtin_amdgcn_global_load_lds(
        (const __attribute__((address_space(1))) unsigned*)g,
        (__attribute__((address_space(3))) unsigned*)l, 16, 0, 0);
}

__device__ __forceinline__ void fma4(float4& c, float s, const float4& v) {
    c.x = fmaf(s, v.x, c.x);
    c.y = fmaf(s, v.y, c.y);
    c.z = fmaf(s, v.z, c.z);
    c.w = fmaf(s, v.w, c.w);
}

// ---------------------------------------------------------------------------
// 1) partial sums part[b][s][c] = sum over 16 rows + emit x as bf16.
//    float4 loads / uint2 bf16 stores; also zeroes the attn-done counter
//    consumed by the next dispatch (dispatch boundary = visibility).
// ---------------------------------------------------------------------------
__global__ __launch_bounds__(384) void mean_kernel(const float* __restrict__ x,
                                                   float* __restrict__ part,
                                                   unsigned short* __restrict__ xb,
                                                   unsigned* __restrict__ done) {
    __shared__ float4 red[4][96];
    const int b = blockIdx.y;
    const int s = blockIdx.x;
    const int tid = threadIdx.x;
    if (b == 0 && s == 0 && tid == 0) *done = 0u;
    const int q  = tid % 96;     // c-quad: covers c = 4q..4q+3
    const int rs = tid / 96;     // row sub-group 0..3

    const size_t row0 = (size_t)(b * N_ + s * 16);
    float4 acc = make_float4(0.f, 0.f, 0.f, 0.f);
#pragma unroll
    for (int i = 0; i < 4; ++i) {
        const size_t row = row0 + rs * 4 + i;
        const float4 v = *(const float4*)(x + row * C_ + q * 4);
        acc.x += v.x; acc.y += v.y; acc.z += v.z; acc.w += v.w;
        *(uint2*)(xb + row * C_ + q * 4) =
            make_uint2(pack2(v.x, v.y), pack2(v.z, v.w));
    }
    red[rs][q] = acc;
    __syncthreads();

    if (tid < 96) {
        const float4 a0 = red[0][tid], a1 = red[1][tid];
        const float4 a2 = red[2][tid], a3 = red[3][tid];
        float4 r;
        r.x = a0.x + a1.x + a2.x + a3.x;
        r.y = a0.y + a1.y + a2.y + a3.y;
        r.z = a0.z + a1.z + a2.z + a3.z;
        r.w = a0.w + a1.w + a2.w + a3.w;
        *(float4*)(part + ((size_t)b * 32 + s) * C_ + tid * 4) = r;
    }
}

// ---------------------------------------------------------------------------
// 2) single dispatch, three roles by blockIdx (no extra launch boundaries):
//    [0,16):    attn[b]  (4-wave coalesced dot) -> release done-counter, exit
//    [16,272):  tm[b,:,:] = sum_k attn[b,k]*tran[k] -> bf16  (acquire-spin
//               until done==16; xw blocks below run during the spin)
//    [272,1040): xw = x @ W^T (bf16 MFMA) -> xwT[b][c][m]   (independent)
//    Deadlock-free: attn blocks are first-dispatched and depend on nothing;
//    xw blocks never wait. Release/acquire at agent scope (r2-validated).
// ---------------------------------------------------------------------------
__global__ __launch_bounds__(256) void tmxw_kernel(const float* __restrict__ tran,
                                                   const float* __restrict__ part,
                                                   const float* __restrict__ centers,
                                                   float* __restrict__ attn,
                                                   unsigned* __restrict__ done,
                                                   unsigned short* __restrict__ tmb,
                                                   const unsigned short* __restrict__ Xb,
                                                   const float* __restrict__ Wf,
                                                   unsigned short* __restrict__ xwT) {
    __shared__ __attribute__((aligned(16))) unsigned short As[64 * 64];
    __shared__ __attribute__((aligned(16))) unsigned short Bs[64 * 64];
    __shared__ float T[4][32 * 35];

    const int tid = threadIdx.x;

    if (blockIdx.x < 16) {
        // ------------------- attn path (16 blocks, 4 waves) -----------------
        float* q_lds = (float*)As;            // 384 floats
        float* redp  = (float*)As + 512;      // 4 floats
        float* pd    = (float*)As + 1024;     // 256 floats
        float* pc    = (float*)Bs;            // 256 floats
        const int b = blockIdx.x;

        float p2 = 0.f;
        for (int c = tid; c < C_; c += 256) {
            const float* pb = part + (size_t)b * 32 * C_ + c;
            float s = 0.f;
#pragma unroll
            for (int i = 0; i < 32; ++i) s += pb[(size_t)i * C_];
            q_lds[c] = s;
            p2 += s * s;
        }
#pragma unroll
        for (int off = 32; off > 0; off >>= 1) p2 += __shfl_xor(p2, off);
        if ((tid & 63) == 0) redp[tid >> 6] = p2;
        __syncthreads();

        {
            const int w    = tid >> 6;        // wave 0..3 -> 96-wide c-chunk
            const int lane = tid & 63;        // lane = k
            const int c0   = w * 96;
            const float* cp = centers + (size_t)c0 * K_ + lane;
            float dot = 0.f, cn2 = 0.f;
#pragma unroll
            for (int i = 0; i < 96; ++i) {
                const float sv = cp[(size_t)i * K_];
                const float qc = q_lds[c0 + i];
                dot = fmaf(qc, sv, dot);
                cn2 = fmaf(sv, sv, cn2);
            }
            pd[w * 64 + lane] = dot;
            pc[w * 64 + lane] = cn2;
        }
        __syncthreads();

        if (tid < 64) {
            float dot = 0.f, cn2 = 0.f;
#pragma unroll
            for (int w = 0; w < 4; ++w) {
                dot += pd[w * 64 + tid];
                cn2 += pc[w * 64 + tid];
            }
            const float qn2 = redp[0] + redp[1] + redp[2] + redp[3];
            const float qnorm = fmaxf(sqrtf(qn2), 1e-12f);
            const float logit = dot / (qnorm * fmaxf(sqrtf(cn2), 1e-12f));

            float m = logit;
#pragma unroll
            for (int off = 32; off > 0; off >>= 1) m = fmaxf(m, __shfl_xor(m, off));
            const float e = expf(logit - m);
            float ssum = e;
#pragma unroll
            for (int off = 32; off > 0; off >>= 1) ssum += __shfl_xor(ssum, off);
            attn[b * K_ + tid] = e / ssum;
        }
        __syncthreads();      // drains the attn stores (vmcnt) before release
        if (tid == 0)
            __hip_atomic_fetch_add(done, 1u, __ATOMIC_RELEASE,
                                   __HIP_MEMORY_SCOPE_AGENT);
        return;
    }

    if (blockIdx.x < 272) {
        // ------------------- tm path (256 blocks) -------------------
        if (tid == 0) {
            while (__hip_atomic_load(done, __ATOMIC_ACQUIRE,
                                     __HIP_MEMORY_SCOPE_AGENT) < 16u)
                __builtin_amdgcn_s_sleep(8);
        }
        __syncthreads();      // all threads ordered after the acquire

        float* a_s = (float*)As;   // [k][b], 1024 floats
        for (int i = tid; i < K_ * B_; i += 256)
            a_s[i] = attn[(i & 15) * K_ + (i >> 4)];
        __syncthreads();

        const size_t j = ((size_t)(blockIdx.x - 16) * 256 + tid) * 4;
        const float* tp = tran + j;
        float4 acc[B_];
#pragma unroll
        for (int b = 0; b < B_; ++b) acc[b] = make_float4(0.f, 0.f, 0.f, 0.f);

        float4 t[8];
#pragma unroll
        for (int i = 0; i < 8; ++i) t[i] = *(const float4*)(tp + (size_t)i * NN_);

        for (int k = 0; k < K_; k += 8) {
            float4 n[8];
            if (k < K_ - 8) {
#pragma unroll
                for (int i = 0; i < 8; ++i)
                    n[i] = *(const float4*)(tp + (size_t)(k + 8 + i) * NN_);
            }
#pragma unroll
            for (int kk = 0; kk < 8; ++kk) {
                const float4* wp = (const float4*)(a_s + (k + kk) * 16);
                const float4 w0 = wp[0], w1 = wp[1], w2 = wp[2], w3 = wp[3];
                const float4 tv = t[kk];
                fma4(acc[0],  w0.x, tv); fma4(acc[1],  w0.y, tv);
                fma4(acc[2],  w0.z, tv); fma4(acc[3],  w0.w, tv);
                fma4(acc[4],  w1.x, tv); fma4(acc[5],  w1.y, tv);
                fma4(acc[6],  w1.z, tv); fma4(acc[7],  w1.w, tv);
                fma4(acc[8],  w2.x, tv); fma4(acc[9],  w2.y, tv);
                fma4(acc[10], w2.z, tv); fma4(acc[11], w2.w, tv);
                fma4(acc[12], w3.x, tv); fma4(acc[13], w3.y, tv);
                fma4(acc[14], w3.z, tv); fma4(acc[15], w3.w, tv);
            }
            if (k < K_ - 8) {
#pragma unroll
                for (int i = 0; i < 8; ++i) t[i] = n[i];
            }
        }
#pragma unroll
        for (int b = 0; b < B_; ++b)
            *(uint2*)(tmb + (size_t)b * NN_ + j) =
                make_uint2(pack2(acc[b].x, acc[b].y), pack2(acc[b].z, acc[b].w));
        return;
    }

    // ------------------- xw path (768 blocks) -------------------
    const int bid  = blockIdx.x - 272;      // [0,768)
    const int row0 = (bid & 127) * 64;
    const int col0 = (bid >> 7) * 64;
    const int lane = tid & 63;
    const int w    = tid >> 6;
    const int wm   = w & 1, wn = w >> 1;
    const int quad = lane >> 4, l15 = lane & 15;

    const int sm = tid >> 3;
    const int sc = tid & 7;

    f32x4 acc[2][2] = {};

    for (int k0 = 0; k0 < C_; k0 += 64) {
        float4 wv[2][2];
#pragma unroll
        for (int p = 0; p < 2; ++p) {
            const int m  = p * 32 + sm;
            const int gc = sc ^ (m & 7);
            const float* src = Wf + (size_t)(col0 + m) * C_ + k0 + gc * 8;
            wv[p][0] = *(const float4*)(src);
            wv[p][1] = *(const float4*)(src + 4);
        }
        __syncthreads();
#pragma unroll
        for (int p = 0; p < 2; ++p) {
            const int m  = p * 32 + sm;
            const int gc = sc ^ (m & 7);
            gl_lds16(Xb + (size_t)(row0 + m) * C_ + k0 + gc * 8,
                     As + (p * 256 + tid) * 8);
            *(uint4*)(Bs + (p * 256 + tid) * 8) =
                make_uint4(pack2(wv[p][0].x, wv[p][0].y),
                           pack2(wv[p][0].z, wv[p][0].w),
                           pack2(wv[p][1].x, wv[p][1].y),
                           pack2(wv[p][1].z, wv[p][1].w));
        }
        __syncthreads();
#pragma unroll
        for (int kk = 0; kk < 2; ++kk) {
            bf16x8 afr[2], bfr[2];
#pragma unroll
            for (int mt = 0; mt < 2; ++mt) {
                const int mr = wm * 32 + mt * 16 + l15;
                const int kc = (kk * 4 + quad) ^ (mr & 7);
                afr[mt] = *(const bf16x8*)(As + mr * 64 + kc * 8);
            }
#pragma unroll
            for (int nt = 0; nt < 2; ++nt) {
                const int nr = wn * 32 + nt * 16 + l15;
                const int kc = (kk * 4 + quad) ^ (nr & 7);
                bfr[nt] = *(const bf16x8*)(Bs + nr * 64 + kc * 8);
            }
#pragma unroll
            for (int mt = 0; mt < 2; ++mt)
#pragma unroll
                for (int nt = 0; nt < 2; ++nt)
                    acc[mt][nt] = __builtin_amdgcn_mfma_f32_16x16x32_bf16(
                        afr[mt], bfr[nt], acc[mt][nt], 0, 0, 0);
        }
    }

#pragma unroll
    for (int mt = 0; mt < 2; ++mt)
#pragma unroll
        for (int nt = 0; nt < 2; ++nt)
#pragma unroll
            for (int r = 0; r < 4; ++r)
                T[w][(mt * 16 + quad * 4 + r) * 35 + nt * 16 + l15] = acc[mt][nt][r];
    __syncthreads();

    const int rw = row0 + wm * 32;
    const int b  = rw >> 9;
    const int m0 = rw & 511;
    const int c0 = col0 + wn * 32;
    unsigned short* dst = xwT + (size_t)b * C_ * N_;
#pragma unroll
    for (int i = 0; i < 8; ++i) {
        const int cl = i * 4 + quad;
        const int ml = l15 * 2;
        const float v0 = T[w][(ml + 0) * 35 + cl];
        const float v1 = T[w][(ml + 1) * 35 + cl];
        *(unsigned*)(dst + (size_t)(c0 + cl) * N_ + m0 + ml) = pack2(v0, v1);
    }
}

// ---------------------------------------------------------------------------
// 3) out[b,n,c] = sum_m tm[b,n,m] * xw[b,m,c] + bias[c]  (bf16 MFMA, fp32 out)
// ---------------------------------------------------------------------------
__global__ __launch_bounds__(256) void out_mfma(const unsigned short* __restrict__ Ab,
                                                const unsigned short* __restrict__ Bt,
                                                const float* __restrict__ bias,
                                                float* __restrict__ out) {
    __shared__ unsigned short As[64 * 64];
    __shared__ unsigned short Bs[64 * 64];

    const int tid  = threadIdx.x;
    const int b    = blockIdx.z;
    const int row0 = blockIdx.x * 64;
    const int col0 = blockIdx.y * 64;
    const int lane = tid & 63;
    const int w    = tid >> 6;
    const int wm   = w & 1, wn = w >> 1;
    const int quad = lane >> 4, l15 = lane & 15;

    const unsigned short* Abase = Ab + (size_t)b * N_ * N_;
    const unsigned short* Bbase = Bt + (size_t)b * C_ * N_;

    const int sm = tid >> 3;
    const int sc = tid & 7;

    f32x4 acc[2][2] = {};

    for (int k0 = 0; k0 < N_; k0 += 64) {
        __syncthreads();
#pragma unroll
        for (int p = 0; p < 2; ++p) {
            const int m  = p * 32 + sm;
            const int gc = sc ^ (m & 7);
            gl_lds16(Abase + (size_t)(row0 + m) * N_ + k0 + gc * 8,
                     As + (p * 256 + tid) * 8);
            gl_lds16(Bbase + (size_t)(col0 + m) * N_ + k0 + gc * 8,
                     Bs + (p * 256 + tid) * 8);
        }
        __syncthreads();
#pragma unroll
        for (int kk = 0; kk < 2; ++kk) {
            bf16x8 afr[2], bfr[2];
#pragma unroll
            for (int mt = 0; mt < 2; ++mt) {
                const int mr = wm * 32 + mt * 16 + l15;
                const int kc = (kk * 4 + quad) ^ (mr & 7);
                afr[mt] = *(const bf16x8*)(As + mr * 64 + kc * 8);
            }
#pragma unroll
            for (int nt = 0; nt < 2; ++nt) {
                const int nr = wn * 32 + nt * 16 + l15;
                const int kc = (kk * 4 + quad) ^ (nr & 7);
                bfr[nt] = *(const bf16x8*)(Bs + nr * 64 + kc * 8);
            }
#pragma unroll
            for (int mt = 0; mt < 2; ++mt)
#pragma unroll
                for (int nt = 0; nt < 2; ++nt)
                    acc[mt][nt] = __builtin_amdgcn_mfma_f32_16x16x32_bf16(
                        afr[mt], bfr[nt], acc[mt][nt], 0, 0, 0);
        }
    }

#pragma unroll
    for (int nt = 0; nt < 2; ++nt) {
        const int c  = col0 + wn * 32 + nt * 16 + l15;
        const float bv = bias[c];
#pragma unroll
        for (int mt = 0; mt < 2; ++mt) {
            const int rbase = row0 + wm * 32 + mt * 16 + quad * 4;
#pragma unroll
            for (int r = 0; r < 4; ++r)
                out[((size_t)(b * N_ + rbase + r)) * C_ + c] = acc[mt][nt][r] + bv;
        }
    }
}

// ---------------------------------------------------------------------------
// launch — 3 dispatches
// ---------------------------------------------------------------------------
extern "C" void kernel_launch(void* const* d_in, const int* in_sizes, int n_in,
                              void* d_out, int out_size, void* d_ws, size_t ws_size,
                              hipStream_t stream) {
    const float* x       = (const float*)d_in[0];   // [16,512,384]
    const float* centers = (const float*)d_in[1];   // [384,64]
    const float* tran    = (const float*)d_in[2];   // [64,512,512]
    const float* proj_w  = (const float*)d_in[3];   // [384,384]
    const float* proj_b  = (const float*)d_in[4];   // [384]
    float* out = (float*)d_out;                     // [16,512,384]

    float* ws   = (float*)d_ws;
    float* part = ws;                                    // 16*32*384 floats
    float* attn = ws + 196608;                           // 1024 floats
    unsigned short* tmb = (unsigned short*)(ws + 197632);        // 16*512*512 bf16
    unsigned short* xwT = tmb + (size_t)B_ * N_ * N_;            // 16*384*512 bf16
    unsigned short* xb  = xwT + (size_t)B_ * C_ * N_;            // 16*512*384 bf16
    unsigned* done = (unsigned*)(xb + (size_t)B_ * N_ * C_);     // 1 counter

    mean_kernel<<<dim3(32, 16), 384, 0, stream>>>(x, part, xb, done);
    tmxw_kernel<<<1040, 256, 0, stream>>>(tran, part, centers, attn, done,
                                          tmb, xb, proj_w, xwT);
    out_mfma<<<dim3(8, 6, 16), 256, 0, stream>>>(tmb, xwT, proj_b, out);
}

// Round 7
// 136.983 us; speedup vs baseline: 1.1339x; 1.1339x over previous
//
#include <hip/hip_runtime.h>
#include <math.h>
#include <stdint.h>

#define B_  16
#define N_  512
#define C_  384
#define K_  64
#define NN_ (N_*N_)   // 262144

typedef short bf16x8 __attribute__((ext_vector_type(8)));
typedef float f32x4  __attribute__((ext_vector_type(4)));

// fp32 -> bf16 round-to-nearest-even (inputs finite, no NaN path needed)
__device__ __forceinline__ unsigned short f2bf(float f) {
    union { float f; unsigned u; } v; v.f = f;
    unsigned r = v.u + 0x7FFF + ((v.u >> 16) & 1);
    return (unsigned short)(r >> 16);
}
__device__ __forceinline__ unsigned pack2(float a, float b) {
    return ((unsigned)f2bf(b) << 16) | f2bf(a);
}

// async 16-B global -> LDS (lane-contiguous LDS dest required)
__device__ __forceinline__ void gl_lds16(const void* g, void* l) {
    __builtin_amdgcn_global_load_lds(
        (const __attribute__((address_space(1))) unsigned*)g,
        (__attribute__((address_space(3))) unsigned*)l, 16, 0, 0);
}

__device__ __forceinline__ void fma4(float4& c, float s, const float4& v) {
    c.x = fmaf(s, v.x, c.x);
    c.y = fmaf(s, v.y, c.y);
    c.z = fmaf(s, v.z, c.z);
    c.w = fmaf(s, v.w, c.w);
}

// ---------------------------------------------------------------------------
// 1) partial sums part[b][s][c] = sum over 16 rows + emit x as bf16.
//    float4 loads (16 B/lane), uint2 bf16 stores, LDS cross-thread reduce.
// ---------------------------------------------------------------------------
__global__ __launch_bounds__(384) void mean_kernel(const float* __restrict__ x,
                                                   float* __restrict__ part,
                                                   unsigned short* __restrict__ xb) {
    __shared__ float4 red[4][96];
    const int b = blockIdx.y;
    const int s = blockIdx.x;
    const int tid = threadIdx.x;
    const int q  = tid % 96;     // c-quad: covers c = 4q..4q+3
    const int rs = tid / 96;     // row sub-group 0..3

    const size_t row0 = (size_t)(b * N_ + s * 16);
    float4 acc = make_float4(0.f, 0.f, 0.f, 0.f);
#pragma unroll
    for (int i = 0; i < 4; ++i) {
        const size_t row = row0 + rs * 4 + i;
        const float4 v = *(const float4*)(x + row * C_ + q * 4);
        acc.x += v.x; acc.y += v.y; acc.z += v.z; acc.w += v.w;
        *(uint2*)(xb + row * C_ + q * 4) =
            make_uint2(pack2(v.x, v.y), pack2(v.z, v.w));
    }
    red[rs][q] = acc;
    __syncthreads();

    if (tid < 96) {
        const float4 a0 = red[0][tid], a1 = red[1][tid];
        const float4 a2 = red[2][tid], a3 = red[3][tid];
        float4 r;
        r.x = a0.x + a1.x + a2.x + a3.x;
        r.y = a0.y + a1.y + a2.y + a3.y;
        r.z = a0.z + a1.z + a2.z + a3.z;
        r.w = a0.w + a1.w + a2.w + a3.w;
        *(float4*)(part + ((size_t)b * 32 + s) * C_ + tid * 4) = r;
    }
}

// ---------------------------------------------------------------------------
// 2) attn[b,k] = softmax_k(cosine(q, centers[:,k]))  (fast coalesced dot:
//    wave w owns c-chunk [64w,64w+64), lane = k; fully-unrolled 64-iter loop)
// ---------------------------------------------------------------------------
__global__ __launch_bounds__(384) void attn_kernel(const float* __restrict__ part,
                                                   const float* __restrict__ centers,
                                                   float* __restrict__ attn) {
    __shared__ float q_lds[C_];
    __shared__ float red[6];
    __shared__ float pd[C_];
    __shared__ float pc[C_];
    const int b = blockIdx.x;
    const int tid = threadIdx.x;

    const float* pb = part + (size_t)b * 32 * C_ + tid;
    float s = 0.f;
#pragma unroll
    for (int i = 0; i < 32; ++i) s += pb[(size_t)i * C_];
    q_lds[tid] = s;
    float p2 = s * s;
#pragma unroll
    for (int off = 32; off > 0; off >>= 1) p2 += __shfl_xor(p2, off);
    if ((tid & 63) == 0) red[tid >> 6] = p2;
    __syncthreads();

    {
        const int w    = tid >> 6;        // wave 0..5 -> c-chunk
        const int lane = tid & 63;        // lane = k
        const int c0   = w * 64;
        const float* cp = centers + (size_t)c0 * K_ + lane;
        float dot = 0.f, cn2 = 0.f;
#pragma unroll
        for (int i = 0; i < 64; ++i) {
            const float sv = cp[(size_t)i * K_];
            const float qc = q_lds[c0 + i];
            dot = fmaf(qc, sv, dot);
            cn2 = fmaf(sv, sv, cn2);
        }
        pd[w * 64 + lane] = dot;
        pc[w * 64 + lane] = cn2;
    }
    __syncthreads();

    if (tid < 64) {
        float dot = 0.f, cn2 = 0.f;
#pragma unroll
        for (int w = 0; w < 6; ++w) {
            dot += pd[w * 64 + tid];
            cn2 += pc[w * 64 + tid];
        }
        const float qn2 = red[0] + red[1] + red[2] + red[3] + red[4] + red[5];
        const float qnorm = fmaxf(sqrtf(qn2), 1e-12f);
        const float logit = dot / (qnorm * fmaxf(sqrtf(cn2), 1e-12f));

        float m = logit;
#pragma unroll
        for (int off = 32; off > 0; off >>= 1) m = fmaxf(m, __shfl_xor(m, off));
        const float e = expf(logit - m);
        float ssum = e;
#pragma unroll
        for (int off = 32; off > 0; off >>= 1) ssum += __shfl_xor(ssum, off);
        attn[b * K_ + tid] = e / ssum;
    }
}

// ---------------------------------------------------------------------------
// 3+4 fused) blocks [0,256):  tm[b,:,:] = sum_k attn[b,k]*tran[k]  -> bf16
//            blocks [256,1024): xw = x @ W^T (bf16 MFMA) -> xwT[b][c][m]
//    No atomics anywhere (agent-scope acquire spins poison the L2s - r6).
//    xw epilogue: direct fragment->xwT stores (C/D layout col=lane&15,
//    row=quad*4+r gives 4 consecutive m per lane -> one aligned 8-B store
//    per fragment). Removes the LDS transpose buffer + one barrier.
// ---------------------------------------------------------------------------
__global__ __launch_bounds__(256) void tmxw_kernel(const float* __restrict__ tran,
                                                   const float* __restrict__ attn,
                                                   unsigned short* __restrict__ tmb,
                                                   const unsigned short* __restrict__ Xb,
                                                   const float* __restrict__ Wf,
                                                   unsigned short* __restrict__ xwT) {
    __shared__ __attribute__((aligned(16))) unsigned short As[64 * 64];
    __shared__ __attribute__((aligned(16))) unsigned short Bs[64 * 64];

    const int tid = threadIdx.x;

    if (blockIdx.x < 256) {
        // ------------------- tm path -------------------
        float* a_s = (float*)As;   // [k][b], 1024 floats
        for (int i = tid; i < K_ * B_; i += 256)
            a_s[i] = attn[(i & 15) * K_ + (i >> 4)];
        __syncthreads();

        const size_t j = ((size_t)blockIdx.x * 256 + tid) * 4;
        const float* tp = tran + j;
        float4 acc[B_];
#pragma unroll
        for (int b = 0; b < B_; ++b) acc[b] = make_float4(0.f, 0.f, 0.f, 0.f);

        float4 t[8];
#pragma unroll
        for (int i = 0; i < 8; ++i) t[i] = *(const float4*)(tp + (size_t)i * NN_);

        for (int k = 0; k < K_; k += 8) {
            float4 n[8];
            if (k < K_ - 8) {
#pragma unroll
                for (int i = 0; i < 8; ++i)
                    n[i] = *(const float4*)(tp + (size_t)(k + 8 + i) * NN_);
            }
#pragma unroll
            for (int kk = 0; kk < 8; ++kk) {
                const float4* wp = (const float4*)(a_s + (k + kk) * 16);
                const float4 w0 = wp[0], w1 = wp[1], w2 = wp[2], w3 = wp[3];
                const float4 tv = t[kk];
                fma4(acc[0],  w0.x, tv); fma4(acc[1],  w0.y, tv);
                fma4(acc[2],  w0.z, tv); fma4(acc[3],  w0.w, tv);
                fma4(acc[4],  w1.x, tv); fma4(acc[5],  w1.y, tv);
                fma4(acc[6],  w1.z, tv); fma4(acc[7],  w1.w, tv);
                fma4(acc[8],  w2.x, tv); fma4(acc[9],  w2.y, tv);
                fma4(acc[10], w2.z, tv); fma4(acc[11], w2.w, tv);
                fma4(acc[12], w3.x, tv); fma4(acc[13], w3.y, tv);
                fma4(acc[14], w3.z, tv); fma4(acc[15], w3.w, tv);
            }
            if (k < K_ - 8) {
#pragma unroll
                for (int i = 0; i < 8; ++i) t[i] = n[i];
            }
        }
#pragma unroll
        for (int b = 0; b < B_; ++b)
            *(uint2*)(tmb + (size_t)b * NN_ + j) =
                make_uint2(pack2(acc[b].x, acc[b].y), pack2(acc[b].z, acc[b].w));
        return;
    }

    // ------------------- xw path -------------------
    const int bid  = blockIdx.x - 256;      // [0,768)
    const int row0 = (bid & 127) * 64;
    const int col0 = (bid >> 7) * 64;
    const int lane = tid & 63;
    const int w    = tid >> 6;
    const int wm   = w & 1, wn = w >> 1;
    const int quad = lane >> 4, l15 = lane & 15;

    const int sm = tid >> 3;
    const int sc = tid & 7;

    f32x4 acc[2][2] = {};

    for (int k0 = 0; k0 < C_; k0 += 64) {
        float4 wv[2][2];
#pragma unroll
        for (int p = 0; p < 2; ++p) {
            const int m  = p * 32 + sm;
            const int gc = sc ^ (m & 7);
            const float* src = Wf + (size_t)(col0 + m) * C_ + k0 + gc * 8;
            wv[p][0] = *(const float4*)(src);
            wv[p][1] = *(const float4*)(src + 4);
        }
        __syncthreads();
#pragma unroll
        for (int p = 0; p < 2; ++p) {
            const int m  = p * 32 + sm;
            const int gc = sc ^ (m & 7);
            gl_lds16(Xb + (size_t)(row0 + m) * C_ + k0 + gc * 8,
                     As + (p * 256 + tid) * 8);
            *(uint4*)(Bs + (p * 256 + tid) * 8) =
                make_uint4(pack2(wv[p][0].x, wv[p][0].y),
                           pack2(wv[p][0].z, wv[p][0].w),
                           pack2(wv[p][1].x, wv[p][1].y),
                           pack2(wv[p][1].z, wv[p][1].w));
        }
        __syncthreads();
#pragma unroll
        for (int kk = 0; kk < 2; ++kk) {
            bf16x8 afr[2], bfr[2];
#pragma unroll
            for (int mt = 0; mt < 2; ++mt) {
                const int mr = wm * 32 + mt * 16 + l15;
                const int kc = (kk * 4 + quad) ^ (mr & 7);
                afr[mt] = *(const bf16x8*)(As + mr * 64 + kc * 8);
            }
#pragma unroll
            for (int nt = 0; nt < 2; ++nt) {
                const int nr = wn * 32 + nt * 16 + l15;
                const int kc = (kk * 4 + quad) ^ (nr & 7);
                bfr[nt] = *(const bf16x8*)(Bs + nr * 64 + kc * 8);
            }
#pragma unroll
            for (int mt = 0; mt < 2; ++mt)
#pragma unroll
                for (int nt = 0; nt < 2; ++nt)
                    acc[mt][nt] = __builtin_amdgcn_mfma_f32_16x16x32_bf16(
                        afr[mt], bfr[nt], acc[mt][nt], 0, 0, 0);
        }
    }

    // direct epilogue: fragment (mt,nt): c = col0+wn*32+nt*16+l15 (per lane),
    // m = (row0&511)+wm*32+mt*16+quad*4 + r, r=0..3 -> one 8-B store/fragment.
    {
        const int rw = row0 + wm * 32;
        const int b  = rw >> 9;
        const int m0 = rw & 511;
        unsigned short* dst = xwT + (size_t)b * C_ * N_;
#pragma unroll
        for (int nt = 0; nt < 2; ++nt) {
            const int c = col0 + wn * 32 + nt * 16 + l15;
#pragma unroll
            for (int mt = 0; mt < 2; ++mt) {
                const int m = m0 + mt * 16 + quad * 4;
                *(uint2*)(dst + (size_t)c * N_ + m) =
                    make_uint2(pack2(acc[mt][nt][0], acc[mt][nt][1]),
                               pack2(acc[mt][nt][2], acc[mt][nt][3]));
            }
        }
    }
}

// ---------------------------------------------------------------------------
// 5) out[b,n,c] = sum_m tm[b,n,m] * xw[b,m,c] + bias[c]  (bf16 MFMA, fp32 out)
// ---------------------------------------------------------------------------
__global__ __launch_bounds__(256) void out_mfma(const unsigned short* __restrict__ Ab,
                                                const unsigned short* __restrict__ Bt,
                                                const float* __restrict__ bias,
                                                float* __restrict__ out) {
    __shared__ unsigned short As[64 * 64];
    __shared__ unsigned short Bs[64 * 64];

    const int tid  = threadIdx.x;
    const int b    = blockIdx.z;
    const int row0 = blockIdx.x * 64;
    const int col0 = blockIdx.y * 64;
    const int lane = tid & 63;
    const int w    = tid >> 6;
    const int wm   = w & 1, wn = w >> 1;
    const int quad = lane >> 4, l15 = lane & 15;

    const unsigned short* Abase = Ab + (size_t)b * N_ * N_;
    const unsigned short* Bbase = Bt + (size_t)b * C_ * N_;

    const int sm = tid >> 3;
    const int sc = tid & 7;

    f32x4 acc[2][2] = {};

    for (int k0 = 0; k0 < N_; k0 += 64) {
        __syncthreads();
#pragma unroll
        for (int p = 0; p < 2; ++p) {
            const int m  = p * 32 + sm;
            const int gc = sc ^ (m & 7);
            gl_lds16(Abase + (size_t)(row0 + m) * N_ + k0 + gc * 8,
                     As + (p * 256 + tid) * 8);
            gl_lds16(Bbase + (size_t)(col0 + m) * N_ + k0 + gc * 8,
                     Bs + (p * 256 + tid) * 8);
        }
        __syncthreads();
#pragma unroll
        for (int kk = 0; kk < 2; ++kk) {
            bf16x8 afr[2], bfr[2];
#pragma unroll
            for (int mt = 0; mt < 2; ++mt) {
                const int mr = wm * 32 + mt * 16 + l15;
                const int kc = (kk * 4 + quad) ^ (mr & 7);
                afr[mt] = *(const bf16x8*)(As + mr * 64 + kc * 8);
            }
#pragma unroll
            for (int nt = 0; nt < 2; ++nt) {
                const int nr = wn * 32 + nt * 16 + l15;
                const int kc = (kk * 4 + quad) ^ (nr & 7);
                bfr[nt] = *(const bf16x8*)(Bs + nr * 64 + kc * 8);
            }
#pragma unroll
            for (int mt = 0; mt < 2; ++mt)
#pragma unroll
                for (int nt = 0; nt < 2; ++nt)
                    acc[mt][nt] = __builtin_amdgcn_mfma_f32_16x16x32_bf16(
                        afr[mt], bfr[nt], acc[mt][nt], 0, 0, 0);
        }
    }

#pragma unroll
    for (int nt = 0; nt < 2; ++nt) {
        const int c  = col0 + wn * 32 + nt * 16 + l15;
        const float bv = bias[c];
#pragma unroll
        for (int mt = 0; mt < 2; ++mt) {
            const int rbase = row0 + wm * 32 + mt * 16 + quad * 4;
#pragma unroll
            for (int r = 0; r < 4; ++r)
                out[((size_t)(b * N_ + rbase + r)) * C_ + c] = acc[mt][nt][r] + bv;
        }
    }
}

// ---------------------------------------------------------------------------
// launch — 4 dispatches, no atomics
// ---------------------------------------------------------------------------
extern "C" void kernel_launch(void* const* d_in, const int* in_sizes, int n_in,
                              void* d_out, int out_size, void* d_ws, size_t ws_size,
                              hipStream_t stream) {
    const float* x       = (const float*)d_in[0];   // [16,512,384]
    const float* centers = (const float*)d_in[1];   // [384,64]
    const float* tran    = (const float*)d_in[2];   // [64,512,512]
    const float* proj_w  = (const float*)d_in[3];   // [384,384]
    const float* proj_b  = (const float*)d_in[4];   // [384]
    float* out = (float*)d_out;                     // [16,512,384]

    float* ws   = (float*)d_ws;
    float* part = ws;                                    // 16*32*384 floats
    float* attn = ws + 196608;                           // 1024 floats
    unsigned short* tmb = (unsigned short*)(ws + 197632);        // 16*512*512 bf16
    unsigned short* xwT = tmb + (size_t)B_ * N_ * N_;            // 16*384*512 bf16
    unsigned short* xb  = xwT + (size_t)B_ * C_ * N_;            // 16*512*384 bf16

    mean_kernel<<<dim3(32, 16), 384, 0, stream>>>(x, part, xb);
    attn_kernel<<<16, 384, 0, stream>>>(part, centers, attn);
    tmxw_kernel<<<1024, 256, 0, stream>>>(tran, attn, tmb, xb, proj_w, xwT);
    out_mfma<<<dim3(8, 6, 16), 256, 0, stream>>>(tmb, xwT, proj_b, out);
}